// Round 10
// baseline (553.351 us; speedup 1.0000x reference)
//
#include <hip/hip_runtime.h>

typedef _Float16 f16x8 __attribute__((ext_vector_type(8)));
typedef float    f32x4 __attribute__((ext_vector_type(4)));

#define NSTEP 512
#define BTB 8       // real batches per block (MFMA B-cols 8..15 duplicate 0..7)

// 7-trans LSTM activation (validated R8/R9: absmax 6.1e-5 over 512 steps).
__device__ __forceinline__ float lstm_act_(float gi, float gf, float gg, float go, float& c) {
    float eg = __expf(fminf(gg + gg, 21.0f));
    float ei = __expf(fminf(-gi, 21.0f));
    float ef = __expf(fminf(-gf, 21.0f));
    float X  = (eg + 1.0f) * (1.0f + ei);
    float Y  = 1.0f + ef;
    float r  = __builtin_amdgcn_rcpf(X * Y);
    c = fmaf(r * X, c, (eg - 1.0f) * (r * Y));
    float ec = __expf(fminf(c + c, 21.0f));
    float eo = __expf(fminf(-go, 21.0f));
    float r2 = __builtin_amdgcn_rcpf((ec + 1.0f) * (1.0f + eo));
    return (ec - 1.0f) * r2;
}
__device__ __forceinline__ float sig_(float v) {
    return __builtin_amdgcn_rcpf(1.0f + __expf(-v));
}
__device__ __forceinline__ float tanh_(float v) {
    return 1.0f - 2.0f * __builtin_amdgcn_rcpf(__expf(v + v) + 1.0f);
}

// 256 threads = 4 waves, grid 512 = 2 INDEPENDENT blocks/CU (de-phased barriers),
// 8 batches/block. Wave w owns tiles tau=4w+tt (tt=0..3) -> units 16w+4tt+q.
// Tile-row = usub*4+gate (R9 mapping). DUPLICATE-COLUMN scheme: every lane reads
// panel row m&7, so B cols 8..15 = cols 0..7 and D cols duplicate; lane m<8
// activates tiles {0,1} (batch m), lane m>=8 tiles {2,3} (batch m-8): exactly
// 2 acts/lane, no DPP, no masking, unique (unit,batch) coverage.
// Carried from R9: fragment-major panel (lane-linear conflict-free ds_read_b128),
// register emb preseed w/ bias-as-MFMA-C (short post-barrier critical path),
// 7-trans activation, f16 weight split W = Whi + Wlo*2^-11.
__global__ __launch_bounds__(256, 2) void lstm_mfma_kernel(
    const float* __restrict__ x,     const float* __restrict__ Wemb,
    const float* __restrict__ Wih1,  const float* __restrict__ Whh1,
    const float* __restrict__ b1,    const float* __restrict__ Wih2,
    const float* __restrict__ b2,    const float* __restrict__ Wout,
    const float* __restrict__ bout,  float* __restrict__ out)
{
    // [buf][kc][q][batch][jj] -> B-frag read addr = base + laneid-linear
    __shared__ __align__(16) _Float16 P[2][2][4][BTB][8];  // 4096 B
    __shared__ __align__(16) float h2tmp[BTB * 64];        // 2048 B
    __shared__ __align__(16) float h2s[256 * BTB];         // 8192 B
    __shared__ float part[32 * BTB * 2];                   // 2048 B

    const int t = threadIdx.x;
    const int l = t & 63;
    const int w = t >> 6;        // wave 0..3
    const int m = l & 15;        // B col / A row; real batch = m&7
    const int q = l >> 4;        // quad
    const int b0 = blockIdx.x * BTB;
    const int mb = m & 7;        // this lane's batch row

    // ---- weight fragments (f16 hi + lo*2048); chunk 0 = emb, 1,2 = h -------
    f16x8 wh[4][3], wl[4][3];
    #pragma unroll
    for (int tt = 0; tt < 4; ++tt) {
        const int n = (m & 3) * 64 + (16 * w + 4 * tt) + (m >> 2);  // gate-row
        #pragma unroll
        for (int c = 0; c < 3; ++c) {
            #pragma unroll
            for (int jj = 0; jj < 8; ++jj) {
                int kk = (q << 3) + jj;
                float v = 0.0f;
                if (c == 0) { if (kk < 20) v = Wih1[n * 20 + kk]; }
                else        { v = Whh1[n * 64 + (c - 1) * 32 + kk]; }
                _Float16 hi = (_Float16)v;
                wh[tt][c][jj] = hi;
                wl[tt][c][jj] = (_Float16)((v - (float)hi) * 2048.0f);
            }
        }
    }
    f32x4 bias4[4];
    #pragma unroll
    for (int tt = 0; tt < 4; ++tt)
        #pragma unroll
        for (int r = 0; r < 4; ++r)
            bias4[tt][r] = b1[r * 64 + 16 * w + 4 * tt + q];
    const f32x4 z4 = {0.f, 0.f, 0.f, 0.f};

    // lane's 2 activation cells: units ubase, ubase+4 at batch mb
    const int ubase = 16 * w + ((m >> 3) << 3) + q;   // m<8: 16w+q ; m>=8: 16w+8+q

    // ---- per-lane emb: 8 We pairs (k = q*8+jj) ------------------------------
    float wea[8], web[8];
    #pragma unroll
    for (int jj = 0; jj < 8; ++jj) {
        int k = (q << 3) + jj;
        wea[jj] = (k < 20) ? Wemb[2 * k]     : 0.0f;
        web[jj] = (k < 20) ? Wemb[2 * k + 1] : 0.0f;
    }
    const float* xrow = x + (size_t)(b0 + mb) * (2 * NSTEP);

    // ---- zero buf 0 (h(-1) = 0) --------------------------------------------
    for (int idx = t; idx < 2 * 4 * BTB * 8; idx += 256)
        ((_Float16*)P[0])[idx] = (_Float16)0.0f;

    // ---- preseed a0/a1 with bias + emb(token 0) -----------------------------
    f32x4 a0[4], a1[4];
    {
        float x0 = xrow[0], x1 = xrow[1];
        f16x8 ef;
        #pragma unroll
        for (int jj = 0; jj < 8; ++jj)
            ef[jj] = (_Float16)fmaxf(fmaf(x0, wea[jj], x1 * web[jj]), 0.0f);
        #pragma unroll
        for (int tt = 0; tt < 4; ++tt) {
            a0[tt] = __builtin_amdgcn_mfma_f32_16x16x32_f16(wh[tt][0], ef, bias4[tt], 0, 0, 0);
            a1[tt] = __builtin_amdgcn_mfma_f32_16x16x32_f16(wl[tt][0], ef, z4, 0, 0, 0);
        }
    }
    float xp0 = xrow[2], xp1 = xrow[3];
    __syncthreads();

    // ---- main recurrence ----------------------------------------------------
    float cst[2] = {0.f, 0.f};
    int cur = 0;

    for (int i = 0; i < NSTEP; ++i) {
        // h(i-1) B-frags: lane-linear; lanes m and m+8 broadcast-read same addr
        const _Float16* base = &P[cur][0][q][mb][0];
        f16x8 f0 = *(const f16x8*)(base);
        f16x8 f1 = *(const f16x8*)(base + 4 * BTB * 8);   // kc=1 plane

        #pragma unroll
        for (int tt = 0; tt < 4; ++tt) {
            a0[tt] = __builtin_amdgcn_mfma_f32_16x16x32_f16(wh[tt][1], f0, a0[tt], 0, 0, 0);
            a1[tt] = __builtin_amdgcn_mfma_f32_16x16x32_f16(wl[tt][1], f0, a1[tt], 0, 0, 0);
            a0[tt] = __builtin_amdgcn_mfma_f32_16x16x32_f16(wh[tt][2], f1, a0[tt], 0, 0, 0);
            a1[tt] = __builtin_amdgcn_mfma_f32_16x16x32_f16(wl[tt][2], f1, a1[tt], 0, 0, 0);
        }

        // pick this lane's 2 tiles: {0,1} for m<8, {2,3} for m>=8 (vector selects)
        const bool hi = (m >= 8);
        f32x4 s0a = hi ? a0[2] : a0[0];
        f32x4 s0b = hi ? a1[2] : a1[0];
        f32x4 s1a = hi ? a0[3] : a0[1];
        f32x4 s1b = hi ? a1[3] : a1[1];

        // activations: (ubase, mb) and (ubase+4, mb)
        const int nxt = cur ^ 1;
        {
            float gi = fmaf(0x1p-11f, s0b[0], s0a[0]);
            float gf = fmaf(0x1p-11f, s0b[1], s0a[1]);
            float gg = fmaf(0x1p-11f, s0b[2], s0a[2]);
            float go = fmaf(0x1p-11f, s0b[3], s0a[3]);
            float hv = lstm_act_(gi, gf, gg, go, cst[0]);
            int u = ubase;
            P[nxt][u >> 5][(u >> 3) & 3][mb][u & 7] = (_Float16)hv;
        }
        {
            float gi = fmaf(0x1p-11f, s1b[0], s1a[0]);
            float gf = fmaf(0x1p-11f, s1b[1], s1a[1]);
            float gg = fmaf(0x1p-11f, s1b[2], s1a[2]);
            float go = fmaf(0x1p-11f, s1b[3], s1a[3]);
            float hv = lstm_act_(gi, gf, gg, go, cst[1]);
            int u = ubase + 4;
            P[nxt][u >> 5][(u >> 3) & 3][mb][u & 7] = (_Float16)hv;
        }

        // preseed a0/a1 with bias + emb(token i+1) (barrier-independent)
        {
            f16x8 ef;
            #pragma unroll
            for (int jj = 0; jj < 8; ++jj)
                ef[jj] = (_Float16)fmaxf(fmaf(xp0, wea[jj], xp1 * web[jj]), 0.0f);
            #pragma unroll
            for (int tt = 0; tt < 4; ++tt) {
                a0[tt] = __builtin_amdgcn_mfma_f32_16x16x32_f16(wh[tt][0], ef, bias4[tt], 0, 0, 0);
                a1[tt] = __builtin_amdgcn_mfma_f32_16x16x32_f16(wl[tt][0], ef, z4, 0, 0, 0);
            }
        }
        int ns = (i + 2 < NSTEP) ? i + 2 : NSTEP - 1;
        xp0 = xrow[2 * ns]; xp1 = xrow[2 * ns + 1];

        __syncthreads();
        cur = nxt;
    }
    // final h(511) in P[cur]

    // ---- epilogue: h64 to fp32 (512 values) --------------------------------
    #pragma unroll
    for (int rep = 0; rep < 2; ++rep) {
        int idx = t + rep * 256;
        int b = idx >> 6, k = idx & 63;
        h2tmp[idx] = (float)P[cur][k >> 5][(k >> 3) & 3][b][k & 7];
    }
    __syncthreads();

    // ---- LSTM2 (single step, h=c=0 -> f-gate irrelevant), u = t ------------
    {
        const int u = t;
        float acci[BTB], accg[BTB], acco[BTB];
        float bi2 = b2[u], bg2 = b2[512 + u], bo2 = b2[768 + u];
        #pragma unroll
        for (int b = 0; b < BTB; ++b) { acci[b] = bi2; accg[b] = bg2; acco[b] = bo2; }
        for (int k4 = 0; k4 < 64; k4 += 4) {
            float4 wi = *(const float4*)&Wih2[(size_t)u * 64 + k4];
            float4 wg = *(const float4*)&Wih2[(size_t)(512 + u) * 64 + k4];
            float4 wo = *(const float4*)&Wih2[(size_t)(768 + u) * 64 + k4];
            #pragma unroll
            for (int b = 0; b < BTB; ++b) {
                float4 hb = *(const float4*)&h2tmp[b * 64 + k4];
                acci[b] += wi.x * hb.x + wi.y * hb.y + wi.z * hb.z + wi.w * hb.w;
                accg[b] += wg.x * hb.x + wg.y * hb.y + wg.z * hb.z + wg.w * hb.w;
                acco[b] += wo.x * hb.x + wo.y * hb.y + wo.z * hb.z + wo.w * hb.w;
            }
        }
        #pragma unroll
        for (int b = 0; b < BTB; ++b) {
            float c2 = sig_(acci[b]) * tanh_(accg[b]);
            h2s[u * BTB + b] = sig_(acco[b]) * tanh_(c2);
        }
    }
    __syncthreads();

    // ---- output projection --------------------------------------------------
    {
        int b = t & 7, grp = t >> 3;             // 32 groups x 8 units
        float p0 = 0.f, p1 = 0.f;
        for (int uu = grp * 8; uu < grp * 8 + 8; ++uu) {
            float hvv = h2s[uu * BTB + b];
            p0 += hvv * Wout[uu];
            p1 += hvv * Wout[256 + uu];
        }
        part[(grp * BTB + b) * 2 + 0] = p0;
        part[(grp * BTB + b) * 2 + 1] = p1;
    }
    __syncthreads();
    if (t < 16) {
        int b = t >> 1, o = t & 1;
        float s0 = bout[o];
        for (int grp = 0; grp < 32; ++grp) s0 += part[(grp * BTB + b) * 2 + o];
        out[(size_t)(b0 + b) * 2 + o] = s0;
    }
}

extern "C" void kernel_launch(void* const* d_in, const int* in_sizes, int n_in,
                              void* d_out, int out_size, void* d_ws, size_t ws_size,
                              hipStream_t stream) {
    const float* x    = (const float*)d_in[0];
    const float* Wemb = (const float*)d_in[1];
    const float* Wih1 = (const float*)d_in[2];
    const float* Whh1 = (const float*)d_in[3];
    const float* b1   = (const float*)d_in[4];
    const float* Wih2 = (const float*)d_in[5];
    // d_in[6] = Whh2: unused (h=c=0 at LSTM2's single step)
    const float* b2   = (const float*)d_in[7];
    const float* Wout = (const float*)d_in[8];
    const float* bout = (const float*)d_in[9];
    float* out = (float*)d_out;

    lstm_mfma_kernel<<<512, 256, 0, stream>>>(
        x, Wemb, Wih1, Whh1, b1, Wih2, b2, Wout, bout, out);
}